// Round 5
// baseline (179.929 us; speedup 1.0000x reference)
//
#include <hip/hip_runtime.h>

typedef _Float16 f16;
typedef __fp16 fp16x2 __attribute__((ext_vector_type(2)));
typedef _Float16 half4 __attribute__((ext_vector_type(4)));
typedef _Float16 half8 __attribute__((ext_vector_type(8)));
typedef float floatx16 __attribute__((ext_vector_type(16)));

#define FSTR 44     // r-dim per field in f16 (42 used; reads of r44..47 hit next field / pad, coeff g=0)
#define XSTR 180    // per-x stride f16: 4*44 + 4 pad = 360 B; 90 dwords (=26 mod 32) -> conflict-free
#define WTOT (32 * XSTR)          // 5760 f16 = 11520 B per wave; 2 waves = 23040 B

union H8 { half8 v; half4 h[2]; fp16x2 p[4]; unsigned u[4]; };
union H4 { half4 v; fp16x2 p[2]; };

// Fused SSIM via MFMA, H-pass then V-pass, per-wave private T^T in LDS.
// ROUND-3 STRUCTURE (best measured: 53.5 us) + two zero-numerics changes:
//  (a) 2 x-tiles per wave, processed sequentially through the SAME LDS T buffer
//      (runtime loop, NOT unrolled -- round-4 lesson: register-resident variants
//      spill; staged prefetch instead: tile-1 m0 loads issued under tile-0 pass2).
//      Bands/epilogue-reduce/atomic paid once per wave instead of twice.
//  (b) XCD-aware block swizzle: default round-robin puts the 4 bx-blocks sharing
//      the same 42 image rows on 4 different XCD L2s; remap so each XCD owns 6
//      contiguous slices and bx-neighbors run consecutively on one XCD.
// Register lessons kept: launch_bounds(128,3) (=170 cap; (128,4) spilled 9.6MB),
// m=1 source rows deduped at oy+36 (rows >=42 multiply g=0), no fences in tail
// (agent-scope fence = L2 writeback on gfx950, 8x regression measured round 1).
// No clip: |clip(x)-x| <= 1e-6, ~500x below fp16-RTZ noise already present.

__device__ __forceinline__ void load_tile(
    const float* __restrict__ img1, const float* __restrict__ img2, size_t base,
    int row, int rowcap, int x0, int q, float4 ra[3][2], float4 rb[3][2], unsigned mk[3])
{
    int rowc = min(max(min(row, rowcap), 0), 511);   // load address (deduped)
    bool rok = (row >= 0) && (row <= 511);           // mask from wanted row
    const float* r1 = img1 + base + (size_t)rowc * 512;
    const float* r2 = img2 + base + (size_t)rowc * 512;
    #pragma unroll
    for (int ch = 0; ch < 3; ++ch) {
        int cb  = x0 - 8 + 16 * ch + 8 * q;      // 8-col chunk, 32B aligned
        int cbc = min(max(cb, 0), 504);
        mk[ch] = (cb == cbc && rok) ? 0xFFFFFFFFu : 0u;
        ra[ch][0] = *(const float4*)(r1 + cbc);
        ra[ch][1] = *(const float4*)(r1 + cbc + 4);
        rb[ch][0] = *(const float4*)(r2 + cbc);
        rb[ch][1] = *(const float4*)(r2 + cbc + 4);
    }
}

__device__ __forceinline__ void compute_acct(
    const float4 ra[3][2], const float4 rb[3][2], const unsigned mk[3],
    const half8 band1[3], floatx16 acc[4])
{
    #pragma unroll
    for (int ch = 0; ch < 3; ++ch) {
        H8 F0, F1, F2, F3;
        #pragma unroll
        for (int h = 0; h < 2; ++h) {
            const float as[4] = {ra[ch][h].x, ra[ch][h].y, ra[ch][h].z, ra[ch][h].w};
            const float bs[4] = {rb[ch][h].x, rb[ch][h].y, rb[ch][h].z, rb[ch][h].w};
            #pragma unroll
            for (int t = 0; t < 2; ++t) {
                float a0 = as[2*t], a1 = as[2*t+1];
                float b0 = bs[2*t], b1 = bs[2*t+1];
                int jj = 2 * h + t;
                F0.p[jj] = __builtin_amdgcn_cvt_pkrtz(a0, a1);
                F1.p[jj] = __builtin_amdgcn_cvt_pkrtz(b0, b1);
                F2.p[jj] = __builtin_amdgcn_cvt_pkrtz(a0*a0 + b0*b0, a1*a1 + b1*b1);
                F3.p[jj] = __builtin_amdgcn_cvt_pkrtz(a0*b0, a1*b1);
            }
        }
        // OOB mask (row clamp / col chunk) as packed AND: {0,1} multiply -> bitmask
        unsigned m = mk[ch];
        #pragma unroll
        for (int i = 0; i < 4; ++i) { F0.u[i] &= m; F1.u[i] &= m; F2.u[i] &= m; F3.u[i] &= m; }
        acc[0] = __builtin_amdgcn_mfma_f32_32x32x16_f16(F0.v, band1[ch], acc[0], 0, 0, 0);
        acc[1] = __builtin_amdgcn_mfma_f32_32x32x16_f16(F1.v, band1[ch], acc[1], 0, 0, 0);
        acc[2] = __builtin_amdgcn_mfma_f32_32x32x16_f16(F2.v, band1[ch], acc[2], 0, 0, 0);
        acc[3] = __builtin_amdgcn_mfma_f32_32x32x16_f16(F3.v, band1[ch], acc[3], 0, 0, 0);
    }
}

// write T^T fields [FLO,FHI) of m-tile MT; D: row r = 8s+4q(+32*MT), col x = ln.
// MT==1,s==1,q==1 would be r44..47 (overlaps next field's r0..3) -> exec-masked off;
// those slots are only ever read against g=0.
template<int MT, int FLO, int FHI>
__device__ __forceinline__ void write_T(f16* tx, int q, const floatx16 acc[4])
{
    #pragma unroll
    for (int f = FLO; f < FHI; ++f) {
        #pragma unroll
        for (int s = 0; s < (MT == 0 ? 4 : 2); ++s) {
            const int r0 = 8 * s + 4 * q + 32 * MT;
            H4 h4;
            h4.p[0] = __builtin_amdgcn_cvt_pkrtz(acc[f][4*s],   acc[f][4*s+1]);
            h4.p[1] = __builtin_amdgcn_cvt_pkrtz(acc[f][4*s+2], acc[f][4*s+3]);
            if (MT == 1 && s == 1) {
                if (q == 0) *(half4*)(tx + f * FSTR + r0) = h4.v;
            } else {
                *(half4*)(tx + f * FSTR + r0) = h4.v;
            }
        }
    }
}

__global__ __launch_bounds__(128, 3) void ssim_kernel(
    const float* __restrict__ img1, const float* __restrict__ img2,
    const float* __restrict__ window, float* __restrict__ acc)
{
    __shared__ __align__(16) f16 smem[2 * WTOT];

    const int tid  = threadIdx.x;
    const int lane = tid & 63;
    const int wv   = tid >> 6;
    const int q    = lane >> 5;
    const int ln   = lane & 31;

    // XCD-aware swizzle: grid (4,16,48) = 3072 blocks; HW round-robins the flat
    // id over 8 XCDs, so orig&7 = XCD. Give XCD k slices 6k..6k+5, bx fastest
    // within -> blocks sharing the same image rows run consecutively on ONE XCD.
    const int orig = blockIdx.x + 4 * blockIdx.y + 64 * blockIdx.z;
    const int nid  = (orig & 7) * 384 + (orig >> 3);    // bijective (3072 % 8 == 0)
    const int bx = nid & 3;
    const int by = (nid >> 2) & 15;
    const int bz = nid >> 6;

    const int c  = bz % 3;
    const int xw = bx * 128 + 64 * wv;                  // wave's 64-col span
    const int oy = by * 32;
    const size_t base = (size_t)bz * (512 * 512);

    f16* Tw = smem + wv * WTOT;                         // wave-private T^T [x32][f4][r44]
    f16* tx = Tw + ln * XSTR;

    // ---- tile-0 m=0 loads in flight under setup ----
    float4 ra[3][2], rb[3][2]; unsigned mk[3];
    load_tile(img1, img2, base, oy - 5 + ln, 511, xw, q, ra, rb, mk);

    // zero each x-slot's 4-f16 pad (read x g=0 by pass2; must be finite)
    if (lane < 32) {
        half4 z4 = {};
        *(half4*)(Tw + lane * XSTR + 176) = z4;
    }

    // per-wave 1-D gaussian: lane t<11 holds g[t] = sum_j w2d[t][j]
    float gv = 0.f;
    if (lane < 11) {
        const float* w2 = window + c * 121 + lane * 11;
        #pragma unroll
        for (int j = 0; j < 11; ++j) gv += w2[j];
    }

    // both bands from ONE shared 11-shuffle gather per ch (x-independent -> shared
    // across both tiles): band1[j] = g[16ch+8q-ln-3+j], band2[j] = gather[j+3]
    half8 band1[3], band2[3];
    #pragma unroll
    for (int ch = 0; ch < 3; ++ch) {
        int ib = 16 * ch + 8 * q - ln - 3;
        float gg[11];
        #pragma unroll
        for (int t = 0; t < 11; ++t) gg[t] = __shfl(gv, (ib + t) & 63, 64);
        H8 t1, t2;
        #pragma unroll
        for (int jj = 0; jj < 4; ++jj) {
            fp16x2 p1 = { (__fp16)gg[2*jj],     (__fp16)gg[2*jj + 1] };
            fp16x2 p2 = { (__fp16)gg[2*jj + 3], (__fp16)gg[2*jj + 4] };
            t1.p[jj] = p1; t2.p[jj] = p2;
        }
        band1[ch] = t1.v; band2[ch] = t2.v;
    }

    float vsum = 0.f;
    const float C1 = 1e-4f, C2 = 9e-4f;

    // ---- two 32-col tiles through the same LDS buffer (runtime loop: no unroll,
    //      no cross-tile register hoisting -- round-4 spill lesson) ----
    for (int t = 0; t < 2; ++t) {
        const int x = xw + (t << 5);

        // this tile's m=1 loads: in flight under accT compute + write_T<0>
        float4 ra1[3][2], rb1[3][2]; unsigned mk1[3];
        load_tile(img1, img2, base, oy + 27 + ln, oy + 36, x, q, ra1, rb1, mk1);

        // pass 1, m=0 (T rows 0..31 = image rows oy-5..oy+26)
        floatx16 accT[4] = {};
        compute_acct(ra, rb, mk, band1, accT);
        write_T<0, 0, 4>(tx, q, accT);

        // pass 1, m=1 (deduped source; only T rows 32..43 consumed)
        floatx16 accU[4] = {};
        compute_acct(ra1, rb1, mk1, band1, accU);
        write_T<1, 0, 4>(tx, q, accU);

        // prefetch next tile's m=0 loads: land under pass2 + epilogue
        if (t == 0)
            load_tile(img1, img2, base, oy - 5 + ln, 511, xw + 32, q, ra, rb, mk);

        // pass 2 (vertical): A-frags = two aligned b64 LDS reads per (ch,f).
        // No barrier: Tw is wave-private; DS ops execute in order per wave.
        floatx16 accH[4] = {};
        #pragma unroll
        for (int ch = 0; ch < 3; ++ch) {
            const f16* tb = Tw + ln * XSTR + 16 * ch + 8 * q;
            #pragma unroll
            for (int f = 0; f < 4; ++f) {
                H8 af;
                af.h[0] = *(const half4*)(tb + f * FSTR);
                af.h[1] = *(const half4*)(tb + f * FSTR + 4);
                accH[f] = __builtin_amdgcn_mfma_f32_32x32x16_f16(af.v, band2[ch], accH[f], 0, 0, 0);
            }
        }

        // epilogue: all 16 outputs per lane valid (exact tiling)
        #pragma unroll
        for (int r = 0; r < 16; ++r) {
            float mu1 = accH[0][r], mu2 = accH[1][r];
            float S = accH[2][r], E12 = accH[3][r];
            float mu11 = mu1 * mu1, mu22 = mu2 * mu2, mu12 = mu1 * mu2;
            float num = (2.f * mu12 + C1) * (2.f * (E12 - mu12) + C2);
            float den = (mu11 + mu22 + C1) * (S - mu11 - mu22 + C2);
            vsum += num * __builtin_amdgcn_rcpf(den);
        }
    }

    // wave reduce -> ONE fire-and-forget atomic per wave, padded per-slice bucket
    #pragma unroll
    for (int off = 32; off > 0; off >>= 1) vsum += __shfl_down(vsum, off, 64);
    if (lane == 0) atomicAdd(&acc[bz * 16], vsum);   // 128 adds/bucket, 48 cachelines
}

__global__ void ssim_finalize(const float* __restrict__ acc,
                              float* __restrict__ out, float invN)
{
    const int lane = threadIdx.x;
    float v = (lane < 48) ? acc[lane * 16] : 0.f;
    #pragma unroll
    for (int off = 32; off > 0; off >>= 1) v += __shfl_down(v, off, 64);
    if (lane == 0) out[0] = 1.0f - v * invN;
}

extern "C" void kernel_launch(void* const* d_in, const int* in_sizes, int n_in,
                              void* d_out, int out_size, void* d_ws, size_t ws_size,
                              hipStream_t stream) {
    const float* img1 = (const float*)d_in[0];
    const float* img2 = (const float*)d_in[1];
    const float* window = (const float*)d_in[2];
    float* out = (float*)d_out;
    float* acc = (float*)d_ws;                      // 48 buckets, stride 16 f32 (64 B)

    const float invN = 1.0f / (16.0f * 3.0f * 512.0f * 512.0f);

    // d_ws is poisoned (0xAA) before every call: zero the buckets
    hipMemsetAsync(acc, 0, 48 * 16 * sizeof(float), stream);

    dim3 block(128);
    dim3 grid(4, 16, 48);                           // 3072 blocks, 2 waves each
    ssim_kernel<<<grid, block, 0, stream>>>(img1, img2, window, acc);
    ssim_finalize<<<1, 64, 0, stream>>>(acc, out, invN);
}

// Round 6
// 152.445 us; speedup vs baseline: 1.1803x; 1.1803x over previous
//
#include <hip/hip_runtime.h>

typedef _Float16 f16;
typedef __fp16 fp16x2 __attribute__((ext_vector_type(2)));
typedef _Float16 half4 __attribute__((ext_vector_type(4)));
typedef _Float16 half8 __attribute__((ext_vector_type(8)));
typedef float floatx16 __attribute__((ext_vector_type(16)));

#define FSTR 44     // r-dim per field in f16 (42 used; reads of r44..47 hit next field / pad, coeff g=0)
#define XSTR 180    // per-x stride f16: 4*44 + 4 pad = 360 B; 90 dwords (=26 mod 32) -> conflict-free
#define WTOT (32 * XSTR)          // 5760 f16 = 11520 B per wave; 2 waves = 23040 B

union H8 { half8 v; half4 h[2]; fp16x2 p[4]; unsigned u[4]; };
union H4 { half4 v; fp16x2 p[2]; };

// Fused SSIM via MFMA, H-pass then V-pass, per-wave private T^T in LDS.
// EXACT ROUND-3 STRUCTURE (verified best: 53.5 us, WRITE_SIZE 384 KB = no spill)
// plus two zero-register-risk changes:
//  (a) XCD-aware block swizzle (pure SALU id remap): per-bz working set ~4 MB
//      fits one XCD's 4 MiB L2; default round-robin interleaves all 48 slices
//      over all 8 XCDs (every XCD streams ~100 MB). Remap so XCD k owns slices
//      6k..6k+5 with bx fastest -> halo/m1-dedup re-reads become L2 hits.
//  (b) band2 built late from gv (just before pass 2) instead of held through
//      pass 1: -12 VGPR at the accT/accU live peak.
// HARD-WON CONSTRAINTS (do not violate):
//  - ONE x-tile per wave. Rounds 4+5 (register pass-2 / 2-tile loop) both spilled
//    (28-65 MB scratch): compile-time loops fully unroll at -O3 and merge live
//    ranges; per-wave state cannot grow past the ~170-reg granule.
//  - launch_bounds(128,3): (128,4) caps at 128 regs -> 9.6 MB spill (rounds 1-2).
//  - No fences in tail: agent-scope fence = L2 writeback on gfx950 (8x, round 1).
//  - m=1 source rows deduped at oy+36: T rows >=42 multiply g=0.
// No clip: |clip(x)-x| <= 1e-6, ~500x below fp16-RTZ noise already present.

__device__ __forceinline__ void load_tile(
    const float* __restrict__ img1, const float* __restrict__ img2, size_t base,
    int row, int rowcap, int x0, int q, float4 ra[3][2], float4 rb[3][2], unsigned mk[3])
{
    int rowc = min(max(min(row, rowcap), 0), 511);   // load address (deduped)
    bool rok = (row >= 0) && (row <= 511);           // mask from wanted row
    const float* r1 = img1 + base + (size_t)rowc * 512;
    const float* r2 = img2 + base + (size_t)rowc * 512;
    #pragma unroll
    for (int ch = 0; ch < 3; ++ch) {
        int cb  = x0 - 8 + 16 * ch + 8 * q;      // 8-col chunk, 32B aligned
        int cbc = min(max(cb, 0), 504);
        mk[ch] = (cb == cbc && rok) ? 0xFFFFFFFFu : 0u;
        ra[ch][0] = *(const float4*)(r1 + cbc);
        ra[ch][1] = *(const float4*)(r1 + cbc + 4);
        rb[ch][0] = *(const float4*)(r2 + cbc);
        rb[ch][1] = *(const float4*)(r2 + cbc + 4);
    }
}

__device__ __forceinline__ void compute_acct(
    const float4 ra[3][2], const float4 rb[3][2], const unsigned mk[3],
    const half8 band1[3], floatx16 acc[4])
{
    #pragma unroll
    for (int ch = 0; ch < 3; ++ch) {
        H8 F0, F1, F2, F3;
        #pragma unroll
        for (int h = 0; h < 2; ++h) {
            const float as[4] = {ra[ch][h].x, ra[ch][h].y, ra[ch][h].z, ra[ch][h].w};
            const float bs[4] = {rb[ch][h].x, rb[ch][h].y, rb[ch][h].z, rb[ch][h].w};
            #pragma unroll
            for (int t = 0; t < 2; ++t) {
                float a0 = as[2*t], a1 = as[2*t+1];
                float b0 = bs[2*t], b1 = bs[2*t+1];
                int jj = 2 * h + t;
                F0.p[jj] = __builtin_amdgcn_cvt_pkrtz(a0, a1);
                F1.p[jj] = __builtin_amdgcn_cvt_pkrtz(b0, b1);
                F2.p[jj] = __builtin_amdgcn_cvt_pkrtz(a0*a0 + b0*b0, a1*a1 + b1*b1);
                F3.p[jj] = __builtin_amdgcn_cvt_pkrtz(a0*b0, a1*b1);
            }
        }
        // OOB mask (row clamp / col chunk) as packed AND: {0,1} multiply -> bitmask
        unsigned m = mk[ch];
        #pragma unroll
        for (int i = 0; i < 4; ++i) { F0.u[i] &= m; F1.u[i] &= m; F2.u[i] &= m; F3.u[i] &= m; }
        acc[0] = __builtin_amdgcn_mfma_f32_32x32x16_f16(F0.v, band1[ch], acc[0], 0, 0, 0);
        acc[1] = __builtin_amdgcn_mfma_f32_32x32x16_f16(F1.v, band1[ch], acc[1], 0, 0, 0);
        acc[2] = __builtin_amdgcn_mfma_f32_32x32x16_f16(F2.v, band1[ch], acc[2], 0, 0, 0);
        acc[3] = __builtin_amdgcn_mfma_f32_32x32x16_f16(F3.v, band1[ch], acc[3], 0, 0, 0);
    }
}

// write T^T fields [FLO,FHI) of m-tile MT; D: row r = 8s+4q(+32*MT), col x = ln.
// MT==1,s==1,q==1 would be r44..47 (overlaps next field's r0..3) -> exec-masked off;
// those slots are only ever read against g=0.
template<int MT, int FLO, int FHI>
__device__ __forceinline__ void write_T(f16* tx, int q, const floatx16 acc[4])
{
    #pragma unroll
    for (int f = FLO; f < FHI; ++f) {
        #pragma unroll
        for (int s = 0; s < (MT == 0 ? 4 : 2); ++s) {
            const int r0 = 8 * s + 4 * q + 32 * MT;
            H4 h4;
            h4.p[0] = __builtin_amdgcn_cvt_pkrtz(acc[f][4*s],   acc[f][4*s+1]);
            h4.p[1] = __builtin_amdgcn_cvt_pkrtz(acc[f][4*s+2], acc[f][4*s+3]);
            if (MT == 1 && s == 1) {
                if (q == 0) *(half4*)(tx + f * FSTR + r0) = h4.v;
            } else {
                *(half4*)(tx + f * FSTR + r0) = h4.v;
            }
        }
    }
}

__device__ __forceinline__ half8 mkband(float gv, int ib) {
    // B[k-block][n=ln] = g[ib + j]; lanes >= 11 hold gv = 0 -> zero taps
    H8 t;
    #pragma unroll
    for (int jj = 0; jj < 4; ++jj) {
        float g0 = __shfl(gv, (ib + 2 * jj)     & 63, 64);
        float g1 = __shfl(gv, (ib + 2 * jj + 1) & 63, 64);
        fp16x2 pp = { (__fp16)g0, (__fp16)g1 };
        t.p[jj] = pp;
    }
    return t.v;
}

__global__ __launch_bounds__(128, 3) void ssim_kernel(
    const float* __restrict__ img1, const float* __restrict__ img2,
    const float* __restrict__ window, float* __restrict__ acc)
{
    __shared__ __align__(16) f16 smem[2 * WTOT];

    const int tid  = threadIdx.x;
    const int lane = tid & 63;
    const int wv   = tid >> 6;
    const int q    = lane >> 5;
    const int ln   = lane & 31;

    // XCD swizzle: grid (8,16,48) = 6144 blocks; HW round-robins flat id over
    // 8 XCDs so orig&7 = XCD. nid = (orig&7)*768 + orig>>3 is bijective
    // (6144 = 8*768): XCD k runs slices 6k..6k+5, bx fastest within a slice.
    const int orig = blockIdx.x + 8 * blockIdx.y + 128 * blockIdx.z;
    const int nid  = (orig & 7) * 768 + (orig >> 3);
    const int bx = nid & 7;
    const int by = (nid >> 3) & 15;
    const int bz = nid >> 7;

    const int c  = bz % 3;
    const int x0 = bx * 64 + 32 * wv;
    const int oy = by * 32;
    const size_t base = (size_t)bz * (512 * 512);

    f16* Tw = smem + wv * WTOT;                    // this wave's T^T [x32][f4][r44] (+4 pad)

    // ---- issue ALL 24 float4 loads up front (both m-tiles in flight) ----
    float4 ra[3][2], rb[3][2]; unsigned mk[3];
    load_tile(img1, img2, base, oy - 5 + ln, 511, x0, q, ra, rb, mk);
    float4 ra1[3][2], rb1[3][2]; unsigned mk1[3];
    load_tile(img1, img2, base, oy + 27 + ln, oy + 36, x0, q, ra1, rb1, mk1);

    // per-wave 1-D gaussian: lane t<11 holds g[t] = sum_j w2d[t][j]
    float gv = 0.f;
    if (lane < 11) {
        const float* w2 = window + c * 121 + lane * 11;
        #pragma unroll
        for (int j = 0; j < 11; ++j) gv += w2[j];
    }

    // zero each x-slot's 4-f16 pad (read x g=0 by pass2; must be finite)
    if (lane < 32) {
        half4 z4 = {};
        *(half4*)(Tw + lane * XSTR + 176) = z4;
    }

    // band1 only (band2 built late: -12 VGPR across the pass-1 live peak)
    half8 band1[3];
    #pragma unroll
    for (int ch = 0; ch < 3; ++ch) band1[ch] = mkband(gv, 16 * ch + 8 * q - ln - 3);

    // ---- pass 1, m=0 (T rows 0..31 = image rows oy-5..oy+26) ----
    floatx16 accT[4] = {};
    compute_acct(ra, rb, mk, band1, accT);
    f16* tx = Tw + ln * XSTR;
    write_T<0, 0, 4>(tx, q, accT);

    // ---- pass 1, m=1 (rows oy+27+ln, deduped source; only T rows 32..43 stored) ----
    floatx16 accU[4] = {};
    compute_acct(ra1, rb1, mk1, band1, accU);
    write_T<1, 0, 4>(tx, q, accU);

    // band2: g[k-n]
    half8 band2[3];
    #pragma unroll
    for (int ch = 0; ch < 3; ++ch) band2[ch] = mkband(gv, 16 * ch + 8 * q - ln);

    // ---- pass 2 (vertical): A-frags = two aligned b64 LDS reads per (ch,f) ----
    // No barrier needed: Tw is wave-private, DS ops ordered in-wave via lgkmcnt.
    floatx16 accH[4] = {};
    #pragma unroll
    for (int ch = 0; ch < 3; ++ch) {
        const f16* tb = Tw + ln * XSTR + 16 * ch + 8 * q;
        #pragma unroll
        for (int f = 0; f < 4; ++f) {
            H8 af;
            af.h[0] = *(const half4*)(tb + f * FSTR);
            af.h[1] = *(const half4*)(tb + f * FSTR + 4);
            accH[f] = __builtin_amdgcn_mfma_f32_32x32x16_f16(af.v, band2[ch], accH[f], 0, 0, 0);
        }
    }

    // ---- epilogue: all 16 outputs per lane valid (exact tiling) ----
    float vsum = 0.f;
    const float C1 = 1e-4f, C2 = 9e-4f;
    #pragma unroll
    for (int r = 0; r < 16; ++r) {
        float mu1 = accH[0][r], mu2 = accH[1][r];
        float S = accH[2][r], E12 = accH[3][r];
        float mu11 = mu1 * mu1, mu22 = mu2 * mu2, mu12 = mu1 * mu2;
        float num = (2.f * mu12 + C1) * (2.f * (E12 - mu12) + C2);
        float den = (mu11 + mu22 + C1) * (S - mu11 - mu22 + C2);
        vsum += num * __builtin_amdgcn_rcpf(den);
    }

    // wave reduce -> ONE fire-and-forget atomic per wave, padded per-slice bucket
    #pragma unroll
    for (int off = 32; off > 0; off >>= 1) vsum += __shfl_down(vsum, off, 64);
    if (lane == 0) atomicAdd(&acc[bz * 16], vsum);   // 256 adds/bucket, 48 cachelines
}

__global__ void ssim_finalize(const float* __restrict__ acc,
                              float* __restrict__ out, float invN)
{
    const int lane = threadIdx.x;
    float v = (lane < 48) ? acc[lane * 16] : 0.f;
    #pragma unroll
    for (int off = 32; off > 0; off >>= 1) v += __shfl_down(v, off, 64);
    if (lane == 0) out[0] = 1.0f - v * invN;
}

extern "C" void kernel_launch(void* const* d_in, const int* in_sizes, int n_in,
                              void* d_out, int out_size, void* d_ws, size_t ws_size,
                              hipStream_t stream) {
    const float* img1 = (const float*)d_in[0];
    const float* img2 = (const float*)d_in[1];
    const float* window = (const float*)d_in[2];
    float* out = (float*)d_out;
    float* acc = (float*)d_ws;                      // 48 buckets, stride 16 f32 (64 B)

    const float invN = 1.0f / (16.0f * 3.0f * 512.0f * 512.0f);

    // d_ws is poisoned (0xAA) before every call: zero the buckets
    hipMemsetAsync(acc, 0, 48 * 16 * sizeof(float), stream);

    dim3 block(128);
    dim3 grid(8, 16, 48);                           // 6144 blocks, 2 waves each
    ssim_kernel<<<grid, block, 0, stream>>>(img1, img2, window, acc);
    ssim_finalize<<<1, 64, 0, stream>>>(acc, out, invN);
}

// Round 7
// 139.872 us; speedup vs baseline: 1.2864x; 1.0899x over previous
//
#include <hip/hip_runtime.h>

typedef _Float16 f16;
typedef __fp16 fp16x2 __attribute__((ext_vector_type(2)));
typedef _Float16 half4 __attribute__((ext_vector_type(4)));
typedef _Float16 half8 __attribute__((ext_vector_type(8)));
typedef float floatx16 __attribute__((ext_vector_type(16)));

#define FSTR 44     // r-dim per field in f16 (42 used; reads of r44..47 hit next field / pad, coeff g=0)
#define XSTR 180    // per-x stride f16: 4*44 + 4 pad = 360 B; 90 dwords (=26 mod 32) -> conflict-free
#define WTOT (32 * XSTR)          // 5760 f16 = 11520 B per wave; 2 waves = 23040 B

union H8 { half8 v; half4 h[2]; fp16x2 p[4]; unsigned u[4]; };
union H4 { half4 v; fp16x2 p[2]; };

// Fused SSIM via MFMA, H-pass then V-pass, per-wave private T^T in LDS.
// BYTE-EXACT ROUND-3 BODY (verified: 53.5 us, WRITE_SIZE 384 KB = spill-free)
// + ONLY the XCD-aware block swizzle (pure SALU id remap, zero register cost).
// Swizzle mechanism VERIFIED round 6: FETCH 92 -> 53 MB (halo/m1-dedup re-reads
// become same-XCD L2 hits when XCD k owns contiguous bz slices 6k..6k+5).
// HARD-WON CONSTRAINTS (each measured, do not violate):
//  - EXACT round-3 ordering/band construction. Round 6's "band2 late" refactor
//    (separate mkband chains, gv live through pass 1) spilled 24 MB scratch.
//    Any source reordering at this pressure is a register gamble.
//  - ONE x-tile per wave. Rounds 4+5 (register pass-2 / 2-tile loop) spilled
//    28-65 MB: compile-time loops fully unroll at -O3 and merge live ranges.
//  - launch_bounds(128,3): (128,4) caps at 128 regs -> 9.6 MB spill (rounds 1-2).
//  - No fences in tail: agent-scope fence = L2 writeback on gfx950 (8x, round 1).
//  - m=1 source rows deduped at oy+36: T rows >=42 multiply g=0.
// No clip: |clip(x)-x| <= 1e-6, ~500x below fp16-RTZ noise already present.

__device__ __forceinline__ void load_tile(
    const float* __restrict__ img1, const float* __restrict__ img2, size_t base,
    int row, int rowcap, int x0, int q, float4 ra[3][2], float4 rb[3][2], unsigned mk[3])
{
    int rowc = min(max(min(row, rowcap), 0), 511);   // load address (deduped)
    bool rok = (row >= 0) && (row <= 511);           // mask from wanted row
    const float* r1 = img1 + base + (size_t)rowc * 512;
    const float* r2 = img2 + base + (size_t)rowc * 512;
    #pragma unroll
    for (int ch = 0; ch < 3; ++ch) {
        int cb  = x0 - 8 + 16 * ch + 8 * q;      // 8-col chunk, 32B aligned
        int cbc = min(max(cb, 0), 504);
        mk[ch] = (cb == cbc && rok) ? 0xFFFFFFFFu : 0u;
        ra[ch][0] = *(const float4*)(r1 + cbc);
        ra[ch][1] = *(const float4*)(r1 + cbc + 4);
        rb[ch][0] = *(const float4*)(r2 + cbc);
        rb[ch][1] = *(const float4*)(r2 + cbc + 4);
    }
}

__device__ __forceinline__ void compute_acct(
    const float4 ra[3][2], const float4 rb[3][2], const unsigned mk[3],
    const half8 band1[3], floatx16 acc[4])
{
    #pragma unroll
    for (int ch = 0; ch < 3; ++ch) {
        H8 F0, F1, F2, F3;
        #pragma unroll
        for (int h = 0; h < 2; ++h) {
            const float as[4] = {ra[ch][h].x, ra[ch][h].y, ra[ch][h].z, ra[ch][h].w};
            const float bs[4] = {rb[ch][h].x, rb[ch][h].y, rb[ch][h].z, rb[ch][h].w};
            #pragma unroll
            for (int t = 0; t < 2; ++t) {
                float a0 = as[2*t], a1 = as[2*t+1];
                float b0 = bs[2*t], b1 = bs[2*t+1];
                int jj = 2 * h + t;
                F0.p[jj] = __builtin_amdgcn_cvt_pkrtz(a0, a1);
                F1.p[jj] = __builtin_amdgcn_cvt_pkrtz(b0, b1);
                F2.p[jj] = __builtin_amdgcn_cvt_pkrtz(a0*a0 + b0*b0, a1*a1 + b1*b1);
                F3.p[jj] = __builtin_amdgcn_cvt_pkrtz(a0*b0, a1*b1);
            }
        }
        // OOB mask (row clamp / col chunk) as packed AND: {0,1} multiply -> bitmask
        unsigned m = mk[ch];
        #pragma unroll
        for (int i = 0; i < 4; ++i) { F0.u[i] &= m; F1.u[i] &= m; F2.u[i] &= m; F3.u[i] &= m; }
        acc[0] = __builtin_amdgcn_mfma_f32_32x32x16_f16(F0.v, band1[ch], acc[0], 0, 0, 0);
        acc[1] = __builtin_amdgcn_mfma_f32_32x32x16_f16(F1.v, band1[ch], acc[1], 0, 0, 0);
        acc[2] = __builtin_amdgcn_mfma_f32_32x32x16_f16(F2.v, band1[ch], acc[2], 0, 0, 0);
        acc[3] = __builtin_amdgcn_mfma_f32_32x32x16_f16(F3.v, band1[ch], acc[3], 0, 0, 0);
    }
}

// write T^T fields [FLO,FHI) of m-tile MT; D: row r = 8s+4q(+32*MT), col x = ln.
// MT==1,s==1,q==1 would be r44..47 (overlaps next field's r0..3) -> exec-masked off;
// those slots are only ever read against g=0.
template<int MT, int FLO, int FHI>
__device__ __forceinline__ void write_T(f16* tx, int q, const floatx16 acc[4])
{
    #pragma unroll
    for (int f = FLO; f < FHI; ++f) {
        #pragma unroll
        for (int s = 0; s < (MT == 0 ? 4 : 2); ++s) {
            const int r0 = 8 * s + 4 * q + 32 * MT;
            H4 h4;
            h4.p[0] = __builtin_amdgcn_cvt_pkrtz(acc[f][4*s],   acc[f][4*s+1]);
            h4.p[1] = __builtin_amdgcn_cvt_pkrtz(acc[f][4*s+2], acc[f][4*s+3]);
            if (MT == 1 && s == 1) {
                if (q == 0) *(half4*)(tx + f * FSTR + r0) = h4.v;
            } else {
                *(half4*)(tx + f * FSTR + r0) = h4.v;
            }
        }
    }
}

__global__ __launch_bounds__(128, 3) void ssim_kernel(
    const float* __restrict__ img1, const float* __restrict__ img2,
    const float* __restrict__ window, float* __restrict__ acc)
{
    __shared__ __align__(16) f16 smem[2 * WTOT];

    const int tid  = threadIdx.x;
    const int lane = tid & 63;
    const int wv   = tid >> 6;
    const int q    = lane >> 5;
    const int ln   = lane & 31;

    // XCD swizzle: grid (8,16,48) = 6144 blocks; HW round-robins flat id over
    // 8 XCDs so orig&7 = XCD. nid = (orig&7)*768 + orig>>3 is bijective
    // (6144 = 8*768): XCD k runs slices 6k..6k+5, bx fastest within a slice.
    const int orig = blockIdx.x + 8 * blockIdx.y + 128 * blockIdx.z;
    const int nid  = (orig & 7) * 768 + (orig >> 3);
    const int bx = nid & 7;
    const int by = (nid >> 3) & 15;
    const int bz = nid >> 7;

    const int c  = bz % 3;
    const int x0 = bx * 64 + 32 * wv;
    const int oy = by * 32;
    const size_t base = (size_t)bz * (512 * 512);

    f16* Tw = smem + wv * WTOT;                    // this wave's T^T [x32][f4][r44] (+4 pad)

    // ---- issue ALL 24 float4 loads up front (both m-tiles in flight) ----
    float4 ra[3][2], rb[3][2]; unsigned mk[3];
    load_tile(img1, img2, base, oy - 5 + ln, 511, x0, q, ra, rb, mk);
    float4 ra1[3][2], rb1[3][2]; unsigned mk1[3];
    load_tile(img1, img2, base, oy + 27 + ln, oy + 36, x0, q, ra1, rb1, mk1);

    // per-wave 1-D gaussian: lane t<11 holds g[t] = sum_j w2d[t][j]
    float gv = 0.f;
    if (lane < 11) {
        const float* w2 = window + c * 121 + lane * 11;
        #pragma unroll
        for (int j = 0; j < 11; ++j) gv += w2[j];
    }

    // zero each x-slot's 4-f16 pad (read x g=0 by pass2; must be finite)
    if (lane < 32) {
        half4 z4 = {};
        *(half4*)(Tw + lane * XSTR + 176) = z4;
    }

    // bands from ONE shared 11-shuffle gather per ch:
    //   band1[j] = g[16ch+8q-ln-3 + j], band2[j] = band-gather[j+3]
    half8 band1[3], band2[3];
    #pragma unroll
    for (int ch = 0; ch < 3; ++ch) {
        int ib = 16 * ch + 8 * q - ln - 3;
        float gg[11];
        #pragma unroll
        for (int t = 0; t < 11; ++t) gg[t] = __shfl(gv, (ib + t) & 63, 64);
        H8 t1, t2;
        #pragma unroll
        for (int jj = 0; jj < 4; ++jj) {
            fp16x2 p1 = { (__fp16)gg[2*jj],     (__fp16)gg[2*jj + 1] };
            fp16x2 p2 = { (__fp16)gg[2*jj + 3], (__fp16)gg[2*jj + 4] };
            t1.p[jj] = p1; t2.p[jj] = p2;
        }
        band1[ch] = t1.v; band2[ch] = t2.v;
    }

    // ---- pass 1, m=0 (rows oy-5+ln) ----
    floatx16 accT[4] = {};
    compute_acct(ra, rb, mk, band1, accT);
    f16* tx = Tw + ln * XSTR;
    write_T<0, 0, 4>(tx, q, accT);

    // ---- pass 1, m=1 (rows oy+27+ln, deduped source; only r32..43 stored) ----
    floatx16 accU[4] = {};
    compute_acct(ra1, rb1, mk1, band1, accU);
    write_T<1, 0, 4>(tx, q, accU);

    // ---- pass 2 (vertical): A-frags = two aligned b64 LDS reads per (ch,f) ----
    // No barrier needed: Tw is wave-private, DS ops ordered in-wave via lgkmcnt.
    floatx16 accH[4] = {};
    #pragma unroll
    for (int ch = 0; ch < 3; ++ch) {
        const f16* tb = Tw + ln * XSTR + 16 * ch + 8 * q;
        #pragma unroll
        for (int f = 0; f < 4; ++f) {
            H8 af;
            af.h[0] = *(const half4*)(tb + f * FSTR);
            af.h[1] = *(const half4*)(tb + f * FSTR + 4);
            accH[f] = __builtin_amdgcn_mfma_f32_32x32x16_f16(af.v, band2[ch], accH[f], 0, 0, 0);
        }
    }

    // ---- epilogue: all 16 outputs per lane valid (exact tiling) ----
    float vsum = 0.f;
    const float C1 = 1e-4f, C2 = 9e-4f;
    #pragma unroll
    for (int r = 0; r < 16; ++r) {
        float mu1 = accH[0][r], mu2 = accH[1][r];
        float S = accH[2][r], E12 = accH[3][r];
        float mu11 = mu1 * mu1, mu22 = mu2 * mu2, mu12 = mu1 * mu2;
        float num = (2.f * mu12 + C1) * (2.f * (E12 - mu12) + C2);
        float den = (mu11 + mu22 + C1) * (S - mu11 - mu22 + C2);
        vsum += num * __builtin_amdgcn_rcpf(den);
    }

    // wave reduce -> ONE fire-and-forget atomic per wave, padded per-slice bucket
    #pragma unroll
    for (int off = 32; off > 0; off >>= 1) vsum += __shfl_down(vsum, off, 64);
    if (lane == 0) atomicAdd(&acc[bz * 16], vsum);   // 256 adds/bucket, 48 cachelines
}

__global__ void ssim_finalize(const float* __restrict__ acc,
                              float* __restrict__ out, float invN)
{
    const int lane = threadIdx.x;
    float v = (lane < 48) ? acc[lane * 16] : 0.f;
    #pragma unroll
    for (int off = 32; off > 0; off >>= 1) v += __shfl_down(v, off, 64);
    if (lane == 0) out[0] = 1.0f - v * invN;
}

extern "C" void kernel_launch(void* const* d_in, const int* in_sizes, int n_in,
                              void* d_out, int out_size, void* d_ws, size_t ws_size,
                              hipStream_t stream) {
    const float* img1 = (const float*)d_in[0];
    const float* img2 = (const float*)d_in[1];
    const float* window = (const float*)d_in[2];
    float* out = (float*)d_out;
    float* acc = (float*)d_ws;                      // 48 buckets, stride 16 f32 (64 B)

    const float invN = 1.0f / (16.0f * 3.0f * 512.0f * 512.0f);

    // d_ws is poisoned (0xAA) before every call: zero the buckets
    hipMemsetAsync(acc, 0, 48 * 16 * sizeof(float), stream);

    dim3 block(128);
    dim3 grid(8, 16, 48);                           // 6144 blocks, 2 waves each
    ssim_kernel<<<grid, block, 0, stream>>>(img1, img2, window, acc);
    ssim_finalize<<<1, 64, 0, stream>>>(acc, out, invN);
}